// Round 10
// baseline (287.151 us; speedup 1.0000x reference)
//
#include <hip/hip_runtime.h>

typedef unsigned int uint;
typedef unsigned short u16;
typedef unsigned char u8;

typedef __attribute__((ext_vector_type(8))) short short8;
typedef __attribute__((ext_vector_type(8))) u16 u16x8;
typedef __attribute__((ext_vector_type(4))) float f32x4;
typedef __attribute__((ext_vector_type(2))) float f32x2;

#define NN 50000
#define EE 1600000
#define ETOT (EE + NN)
#define NBUCK 782            // ceil(NN/64)
#define ACHUNK 8192
#define NSC ((ETOT + ACHUNK - 1) / ACHUNK)   // scatter blocks = 202
#define CAP 2432             // per-bucket capacity (mean 2112, +7 sigma)
#define NSLOT 64
#define SLOTW 260
#define GEMM_BLOCKS ((NN + 127) / 128)       // 391

__device__ __forceinline__ u16 f2bf(float f) {
  uint u = __builtin_bit_cast(uint, f);
  uint r = u + 0x7fffu + ((u >> 16) & 1u);
  return (u16)(r >> 16);
}
__device__ __forceinline__ u8 f2fp8(float f) {
  int t = __builtin_amdgcn_cvt_pk_fp8_f32(f, f, 0, false);
  return (u8)(t & 0xff);
}
__device__ __forceinline__ float wred_sum(float v) {
#pragma unroll
  for (int off = 32; off > 0; off >>= 1) v += __shfl_xor(v, off);
  return v;
}
__device__ __forceinline__ uint wred_sum_u(uint v) {
#pragma unroll
  for (int off = 32; off > 0; off >>= 1) v += __shfl_xor(v, off);
  return v;
}

// ---------------- zero: bnxt + pool slots ----------------
__global__ void zero_ws(uint* __restrict__ bnxt, float* __restrict__ slots) {
  int t = threadIdx.x;
  for (int i = t; i < NBUCK; i += 1024) bnxt[i] = 0u;
  for (int i = t; i < NSLOT * SLOTW; i += 1024) slots[i] = 0.f;
}

// ---------------- fused: bucket scatter (blocks < NSC) + W transpose (rest) ----------------
__global__ __launch_bounds__(256) void scat_wt(const int* __restrict__ esrc,
                                               const int* __restrict__ edst,
                                               uint* __restrict__ bnxt,
                                               uint* __restrict__ tmp,
                                               const float* __restrict__ W0,
                                               const float* __restrict__ W1,
                                               u16* __restrict__ Wt0,
                                               u16* __restrict__ Wt1) {
  __shared__ uint lh[NBUCK];
  if (blockIdx.x < NSC) {
    int base = blockIdx.x * ACHUNK;
    int nE = ETOT - base; if (nE > ACHUNK) nE = ACHUNK;
    for (int i = threadIdx.x; i < NBUCK; i += 256) lh[i] = 0;
    __syncthreads();
    for (int k = threadIdx.x; k < nE; k += 256) {
      int e = base + k;
      int d = (e < EE) ? edst[e] : (e - EE);
      atomicAdd(&lh[d >> 6], 1u);
    }
    __syncthreads();
    for (int i = threadIdx.x; i < NBUCK; i += 256) {
      uint c = lh[i];
      lh[i] = c ? atomicAdd(&bnxt[i], c) : 0u;
    }
    __syncthreads();
    for (int k = threadIdx.x; k < nE; k += 256) {
      int e = base + k;
      int s, d;
      if (e < EE) { s = esrc[e]; d = edst[e]; } else { s = e - EE; d = s; }
      uint pos = atomicAdd(&lh[d >> 6], 1u);
      tmp[(size_t)(d >> 6) * CAP + pos] = ((uint)(d & 63) << 16) | (uint)s;
    }
  } else {
    int i = (blockIdx.x - NSC) * 256 + threadIdx.x;
    if (i < 768 * 256) {
      int k = i >> 8, n = i & 255;
      Wt0[n * 768 + k] = f2bf(W0[i]);
    } else if (i < 768 * 256 + 256 * 256) {
      int j = i - 768 * 256;
      int k = j >> 8, n = j & 255;
      Wt1[n * 256 + k] = f2bf(W1[j]);
    }
  }
}

// ---------------- GEMM body (shared-arena based) ----------------
template <bool ABF16>
__device__ __forceinline__ void gemm_body(char* smem, int bx, const void* __restrict__ Avoid,
                                          const u16* __restrict__ Bt, u8* __restrict__ C8,
                                          const float* __restrict__ a_src,
                                          const float* __restrict__ a_dst,
                                          float* __restrict__ as_, float* __restrict__ ad_,
                                          int M, int K) {
  u16* As = (u16*)smem;                      // 16384 B
  u16* Bs = (u16*)(smem + 16384);            // 32768 B
  float* asL = (float*)(smem + 49152);       // 2048 B
  float* adL = (float*)(smem + 51200);       // 2048 B
  const int m0 = bx * 128;
  const int tid = threadIdx.x;
  const int lane = tid & 63;
  const int wv = tid >> 6;
  const int wm = wv >> 2, wn = wv & 3;

  f32x4 acc[4][4] = {};

  const int sr = tid >> 2;
  const int skc = (tid & 3) * 16;
  const int br = tid >> 1;
  const int bk = (tid & 1) * 32;

  for (int k0 = 0; k0 < K; k0 += 64) {
    {
      int grow = m0 + sr;
      if constexpr (!ABF16) {
        const float* A = (const float*)Avoid;
        float4 f[4];
        if (grow < M) {
          const float4* src = reinterpret_cast<const float4*>(A + (size_t)grow * K + k0 + skc);
#pragma unroll
          for (int i = 0; i < 4; ++i) f[i] = src[i];
        } else {
#pragma unroll
          for (int i = 0; i < 4; ++i) f[i] = make_float4(0.f, 0.f, 0.f, 0.f);
        }
#pragma unroll
        for (int i = 0; i < 2; ++i) {
          u16x8 v;
          v[0] = f2bf(f[2 * i].x); v[1] = f2bf(f[2 * i].y);
          v[2] = f2bf(f[2 * i].z); v[3] = f2bf(f[2 * i].w);
          v[4] = f2bf(f[2 * i + 1].x); v[5] = f2bf(f[2 * i + 1].y);
          v[6] = f2bf(f[2 * i + 1].z); v[7] = f2bf(f[2 * i + 1].w);
          int k = skc + i * 8;
          int idx = (sr << 6) + (k ^ ((sr & 7) << 3));
          *reinterpret_cast<u16x8*>(&As[idx]) = v;
        }
      } else {
        const u16* A = (const u16*)Avoid;
        u16x8 v[2];
        if (grow < M) {
          const u16x8* src = reinterpret_cast<const u16x8*>(A + (size_t)grow * K + k0 + skc);
          v[0] = src[0]; v[1] = src[1];
        } else {
          v[0] = (u16x8)0; v[1] = (u16x8)0;
        }
#pragma unroll
        for (int i = 0; i < 2; ++i) {
          int k = skc + i * 8;
          int idx = (sr << 6) + (k ^ ((sr & 7) << 3));
          *reinterpret_cast<u16x8*>(&As[idx]) = v[i];
        }
      }
    }
    {
      const u16x8* src = reinterpret_cast<const u16x8*>(Bt + (size_t)br * K + k0 + bk);
#pragma unroll
      for (int i = 0; i < 4; ++i) {
        u16x8 v = src[i];
        int k = bk + i * 8;
        int idx = (br << 6) + (k ^ ((br & 7) << 3));
        *reinterpret_cast<u16x8*>(&Bs[idx]) = v;
      }
    }
    __syncthreads();
#pragma unroll
    for (int kk = 0; kk < 2; ++kk) {
      short8 af[4], bfr[4];
      const int kb = kk * 32 + (lane >> 4) * 8;
#pragma unroll
      for (int m = 0; m < 4; ++m) {
        int r = wm * 64 + m * 16 + (lane & 15);
        int idx = (r << 6) + (kb ^ ((r & 7) << 3));
        af[m] = *reinterpret_cast<const short8*>(&As[idx]);
      }
#pragma unroll
      for (int n = 0; n < 4; ++n) {
        int c = wn * 64 + n * 16 + (lane & 15);
        int idx = (c << 6) + (kb ^ ((c & 7) << 3));
        bfr[n] = *reinterpret_cast<const short8*>(&Bs[idx]);
      }
#pragma unroll
      for (int m = 0; m < 4; ++m)
#pragma unroll
        for (int n = 0; n < 4; ++n)
          acc[m][n] = __builtin_amdgcn_mfma_f32_16x16x32_bf16(af[m], bfr[n], acc[m][n], 0, 0, 0);
    }
    __syncthreads();
  }

  const int g = lane >> 4;
  const int cl = lane & 15;
  float asv[4], adv[4];
#pragma unroll
  for (int n = 0; n < 4; ++n) {
    int c = wn * 64 + n * 16 + cl;
    asv[n] = a_src[c];
    adv[n] = a_dst[c];
  }
#pragma unroll
  for (int m = 0; m < 4; ++m) {
#pragma unroll
    for (int reg = 0; reg < 4; ++reg) {
      int rl = wm * 64 + m * 16 + g * 4 + reg;
      int row = m0 + rl;
      float ps = 0.f, pd = 0.f;
      if (row < M) {
#pragma unroll
        for (int n = 0; n < 4; ++n) {
          float v = acc[m][n][reg];
          C8[(size_t)row * 256 + wn * 64 + n * 16 + cl] = f2fp8(v);
          ps = fmaf(v, asv[n], ps);
          pd = fmaf(v, adv[n], pd);
        }
      }
#pragma unroll
      for (int off = 1; off < 16; off <<= 1) {
        ps += __shfl_xor(ps, off);
        pd += __shfl_xor(pd, off);
      }
      if (cl == 0) {
        asL[wn * 128 + rl] = ps;
        adL[wn * 128 + rl] = pd;
      }
    }
  }
  __syncthreads();
  if (tid < 128) {
    int row = m0 + tid;
    if (row < M) {
      as_[row] = asL[tid] + asL[128 + tid] + asL[256 + tid] + asL[384 + tid];
      ad_[row] = adL[tid] + adL[128 + tid] + adL[256 + tid] + adL[384 + tid];
    }
  }
}

// ---------------- bucket sort body (inline prefix scan; shared-arena based) ----------------
__device__ __forceinline__ void sort_body(char* smem, int b, const uint* __restrict__ tmp,
                                          const uint* __restrict__ bnxt,
                                          uint* __restrict__ row_ptr, u16* __restrict__ csr) {
  uint* lh = (uint*)smem;                    // 64 u32
  uint* red = (uint*)(smem + 256);           // 8 u32
  uint* buf = (uint*)(smem + 512);           // CAP u32
  int tid = threadIdx.x;
  int lane = tid & 63, wv = tid >> 6;

  // inline exclusive prefix: s0 = sum bnxt[0..b)
  uint part = 0;
  for (int i = tid; i < b; i += 512) part += bnxt[i];
  part = wred_sum_u(part);
  if (lane == 0) red[wv] = part;
  int cnt = (int)bnxt[b];
  if (tid < 64) lh[tid] = 0;
  __syncthreads();
  uint s0 = red[0] + red[1] + red[2] + red[3] + red[4] + red[5] + red[6] + red[7];

  for (int i = tid; i < cnt; i += 512) {
    uint v = tmp[(size_t)b * CAP + i];
    buf[i] = v;
    atomicAdd(&lh[v >> 16], 1u);
  }
  __syncthreads();
  if (tid < 64) {
    uint v = lh[tid];
    uint x = v;
#pragma unroll
    for (int off = 1; off < 64; off <<= 1) {
      uint t = __shfl_up(x, off);
      if (tid >= off) x += t;
    }
    uint pos = s0 + x - v;
    int d = b * 64 + tid;
    if (d < NN) row_ptr[d] = pos;
    lh[tid] = pos;
    if (b == NBUCK - 1 && tid == 0) row_ptr[NN] = s0 + (uint)cnt;
  }
  __syncthreads();
  for (int i = tid; i < cnt; i += 512) {
    uint v = buf[i];
    uint pos = atomicAdd(&lh[v >> 16], 1u);
    csr[pos] = (u16)(v & 0xFFFFu);
  }
}

// ---------------- fused: bucket_sort (blocks < nsort) + GEMM (rest) ----------------
template <bool ABF16>
__global__ __launch_bounds__(512) void gemm_sort(const void* __restrict__ Avoid,
                                                 const u16* __restrict__ Bt,
                                                 u8* __restrict__ C8,
                                                 const float* __restrict__ a_src,
                                                 const float* __restrict__ a_dst,
                                                 float* __restrict__ as_,
                                                 float* __restrict__ ad_,
                                                 int M, int K, int nsort,
                                                 const uint* __restrict__ tmp,
                                                 const uint* __restrict__ bnxt,
                                                 uint* __restrict__ row_ptr,
                                                 u16* __restrict__ csr) {
  __shared__ __align__(16) char smem[53248];
  if ((int)blockIdx.x < nsort) {
    sort_body(smem, blockIdx.x, tmp, bnxt, row_ptr, csr);
  } else {
    gemm_body<ABF16>(smem, blockIdx.x - nsort, Avoid, Bt, C8, a_src, a_dst, as_, ad_, M, K);
  }
}

// decode 16 fp8 from uint4 and fma into acc[16] with weight wg
#define FMA16(v, wg)                                                                   \
  do {                                                                                 \
    f32x2 p_;                                                                          \
    p_ = __builtin_amdgcn_cvt_pk_f32_fp8((v).x, false);                                \
    acc[0] = fmaf((wg), p_.x, acc[0]); acc[1] = fmaf((wg), p_.y, acc[1]);              \
    p_ = __builtin_amdgcn_cvt_pk_f32_fp8((v).x, true);                                 \
    acc[2] = fmaf((wg), p_.x, acc[2]); acc[3] = fmaf((wg), p_.y, acc[3]);              \
    p_ = __builtin_amdgcn_cvt_pk_f32_fp8((v).y, false);                                \
    acc[4] = fmaf((wg), p_.x, acc[4]); acc[5] = fmaf((wg), p_.y, acc[5]);              \
    p_ = __builtin_amdgcn_cvt_pk_f32_fp8((v).y, true);                                 \
    acc[6] = fmaf((wg), p_.x, acc[6]); acc[7] = fmaf((wg), p_.y, acc[7]);              \
    p_ = __builtin_amdgcn_cvt_pk_f32_fp8((v).z, false);                                \
    acc[8] = fmaf((wg), p_.x, acc[8]); acc[9] = fmaf((wg), p_.y, acc[9]);              \
    p_ = __builtin_amdgcn_cvt_pk_f32_fp8((v).z, true);                                 \
    acc[10] = fmaf((wg), p_.x, acc[10]); acc[11] = fmaf((wg), p_.y, acc[11]);          \
    p_ = __builtin_amdgcn_cvt_pk_f32_fp8((v).w, false);                                \
    acc[12] = fmaf((wg), p_.x, acc[12]); acc[13] = fmaf((wg), p_.y, acc[13]);          \
    p_ = __builtin_amdgcn_cvt_pk_f32_fp8((v).w, true);                                 \
    acc[14] = fmaf((wg), p_.x, acc[14]); acc[15] = fmaf((wg), p_.y, acc[15]);          \
  } while (0)

// ---------------- GAT aggregation (fp8 gather, no-LDS epilogue); POOL fuses pooling ----------------
template <bool POOL>
__global__ __launch_bounds__(256) void agg_kernel(const uint4* __restrict__ h16,
                                                  const float* __restrict__ as_,
                                                  const float* __restrict__ ad_,
                                                  const uint* __restrict__ row_ptr,
                                                  const u16* __restrict__ csr_src,
                                                  const float* __restrict__ bias,
                                                  u16* __restrict__ out,
                                                  const float* __restrict__ gate_w,
                                                  float* __restrict__ slots, int n) {
  __shared__ float lp[257];
  int wv = threadIdx.x >> 6;
  int wid = blockIdx.x * 4 + wv;
  int lane = threadIdx.x & 63;
  int g = lane >> 4, li = lane & 15;
  if (POOL) {
    for (int i = threadIdx.x; i < 257; i += 256) lp[i] = 0.f;
    __syncthreads();
  }
  if (wid < n) {
    uint start = row_ptr[wid], end = row_ptr[wid + 1];
    float adi = ad_[wid];
    float acc[16];
#pragma unroll
    for (int c = 0; c < 16; ++c) acc[c] = 0.f;
    float denom = 0.f;
    for (uint base = start; base < end; base += 64) {
      int cnt = (int)(end - base);
      if (cnt > 64) cnt = 64;
      float w = 0.f;
      int s = 0;
      if (lane < cnt) {
        s = (int)csr_src[base + lane];
        float e = as_[s] + adi;
        e = e > 0.f ? e : 0.2f * e;
        w = __expf(e);
      }
      denom += w;
      int j = 0;
      for (; j + 16 <= cnt; j += 16) {
        int s0 = __shfl(s, j + g);
        int s1 = __shfl(s, j + 4 + g);
        int s2 = __shfl(s, j + 8 + g);
        int s3 = __shfl(s, j + 12 + g);
        float w0 = __shfl(w, j + g);
        float w1 = __shfl(w, j + 4 + g);
        float w2 = __shfl(w, j + 8 + g);
        float w3 = __shfl(w, j + 12 + g);
        uint4 v0 = h16[(size_t)s0 * 16 + li];
        uint4 v1 = h16[(size_t)s1 * 16 + li];
        uint4 v2 = h16[(size_t)s2 * 16 + li];
        uint4 v3 = h16[(size_t)s3 * 16 + li];
        FMA16(v0, w0);
        FMA16(v1, w1);
        FMA16(v2, w2);
        FMA16(v3, w3);
      }
      for (; j < cnt; j += 4) {
        int jg = j + g;
        int sg = __shfl(s, jg & 63);
        float wg = __shfl(w, jg & 63);
        if (jg >= cnt) wg = 0.f;
        uint4 v = h16[(size_t)sg * 16 + li];
        FMA16(v, wg);
      }
    }
    denom = wred_sum(denom);
    // cross-group reduction in registers (lanes differing in bits 4,5 hold partials of same li)
#pragma unroll
    for (int c = 0; c < 16; ++c) {
      acc[c] += __shfl_xor(acc[c], 16);
      acc[c] += __shfl_xor(acc[c], 32);
    }
    // lane (li, g) takes cols li*16 + 4g + {0..3}; static extraction via 4-way branch
    float t0, t1, t2, t3;
    if (g == 0)      { t0 = acc[0];  t1 = acc[1];  t2 = acc[2];  t3 = acc[3];  }
    else if (g == 1) { t0 = acc[4];  t1 = acc[5];  t2 = acc[6];  t3 = acc[7];  }
    else if (g == 2) { t0 = acc[8];  t1 = acc[9];  t2 = acc[10]; t3 = acc[11]; }
    else             { t0 = acc[12]; t1 = acc[13]; t2 = acc[14]; t3 = acc[15]; }
    const int fidx = li * 4 + g;            // float4 index of this lane's 4 cols
    float inv = 1.f / (denom + 1e-16f);
    float4 b = reinterpret_cast<const float4*>(bias)[fidx];
    float ox = fmaxf(fmaf(t0, inv, b.x), 0.f);
    float oy = fmaxf(fmaf(t1, inv, b.y), 0.f);
    float oz = fmaxf(fmaf(t2, inv, b.z), 0.f);
    float ow = fmaxf(fmaf(t3, inv, b.w), 0.f);
    if (!POOL) {
      uint2 o;
      o.x = ((uint)f2bf(oy) << 16) | f2bf(ox);
      o.y = ((uint)f2bf(ow) << 16) | f2bf(oz);
      reinterpret_cast<uint2*>(out)[(size_t)wid * 64 + fidx] = o;
    } else {
      float4 gv = reinterpret_cast<const float4*>(gate_w)[fidx];
      float pg = wred_sum(ox * gv.x + oy * gv.y + oz * gv.z + ow * gv.w);
      float we = __expf(pg);
      int c0 = fidx * 4;
      atomicAdd(&lp[c0 + 0], we * ox);
      atomicAdd(&lp[c0 + 1], we * oy);
      atomicAdd(&lp[c0 + 2], we * oz);
      atomicAdd(&lp[c0 + 3], we * ow);
      if (lane == 0) atomicAdd(&lp[256], we);
    }
  }
  if (POOL) {
    __syncthreads();
    int slot = blockIdx.x & (NSLOT - 1);
    for (int i = threadIdx.x; i < 257; i += 256) {
      float v = lp[i];
      if (v != 0.f) atomicAdd(&slots[slot * SLOTW + i], v);
    }
  }
}

// ---------------- final: reduce slots, normalize ----------------
__global__ void pool3_kernel(const float* __restrict__ slots, float* __restrict__ out) {
  __shared__ float dsh;
  int tid = threadIdx.x;
  float acc = 0.f;
  for (int s = 0; s < NSLOT; ++s) acc += slots[s * SLOTW + tid];
  if (tid == 0) {
    float d = 0.f;
    for (int s = 0; s < NSLOT; ++s) d += slots[s * SLOTW + 256];
    dsh = d;
  }
  __syncthreads();
  out[tid] = acc / dsh;
}

// ---------------- launch ----------------
extern "C" void kernel_launch(void* const* d_in, const int* in_sizes, int n_in,
                              void* d_out, int out_size, void* d_ws, size_t ws_size,
                              hipStream_t stream) {
  const float* x = (const float*)d_in[0];
  const int* edge = (const int*)d_in[1];
  const float* W0 = (const float*)d_in[2];
  const float* a_src0 = (const float*)d_in[3];
  const float* a_dst0 = (const float*)d_in[4];
  const float* b0 = (const float*)d_in[5];
  const float* W1 = (const float*)d_in[6];
  const float* a_src1 = (const float*)d_in[7];
  const float* a_dst1 = (const float*)d_in[8];
  const float* b1 = (const float*)d_in[9];
  const float* gate_w = (const float*)d_in[10];
  float* out = (float*)d_out;

  char* p = (char*)d_ws;
  size_t off = 0;
  auto take = [&](size_t bytes) -> char* {
    char* r = p + off;
    off = (off + bytes + 255) & ~(size_t)255;
    return r;
  };
  u8* hA = (u8*)take((size_t)NN * 256);          // fp8 h (GEMM out, gather operand)
  u16* hB = (u16*)take((size_t)NN * 256 * 2);    // bf16 agg0 out (gemm1 input)
  u16* Wt0 = (u16*)take((size_t)256 * 768 * 2);
  u16* Wt1 = (u16*)take((size_t)256 * 256 * 2);
  float* as0 = (float*)take((size_t)NN * 4);
  float* ad0 = (float*)take((size_t)NN * 4);
  float* as1 = (float*)take((size_t)NN * 4);
  float* ad1 = (float*)take((size_t)NN * 4);
  float* slots = (float*)take((size_t)NSLOT * SLOTW * 4);
  uint* bnxt = (uint*)take((size_t)NBUCK * 4);
  uint* row_ptr = (uint*)take((size_t)(NN + 1) * 4);
  uint* tmp = (uint*)take((size_t)NBUCK * CAP * 4);
  u16* csr = (u16*)take((size_t)ETOT * 2);

  const int* edge_src = edge;
  const int* edge_dst = edge + EE;

  zero_ws<<<1, 1024, 0, stream>>>(bnxt, slots);
  scat_wt<<<NSC + 1024, 256, 0, stream>>>(edge_src, edge_dst, bnxt, tmp, W0, W1, Wt0, Wt1);

  // layer 0 GEMM fused with bucket_sort (independent work, hidden under GEMM)
  gemm_sort<false><<<NBUCK + GEMM_BLOCKS, 512, 0, stream>>>(
      x, Wt0, hA, a_src0, a_dst0, as0, ad0, NN, 768, NBUCK, tmp, bnxt, row_ptr, csr);
  agg_kernel<false><<<12500, 256, 0, stream>>>((const uint4*)hA, as0, ad0, row_ptr, csr, b0, hB,
                                               gate_w, slots, NN);
  gemm_sort<true><<<GEMM_BLOCKS, 512, 0, stream>>>(
      hB, Wt1, hA, a_src1, a_dst1, as1, ad1, NN, 256, 0, tmp, bnxt, row_ptr, csr);
  agg_kernel<true><<<12500, 256, 0, stream>>>((const uint4*)hA, as1, ad1, row_ptr, csr, b1, nullptr,
                                              gate_w, slots, NN);

  pool3_kernel<<<1, 256, 0, stream>>>(slots, out);
}

// Round 11
// 277.808 us; speedup vs baseline: 1.0336x; 1.0336x over previous
//
#include <hip/hip_runtime.h>

typedef unsigned int uint;
typedef unsigned short u16;
typedef unsigned char u8;

typedef __attribute__((ext_vector_type(8))) short short8;
typedef __attribute__((ext_vector_type(8))) u16 u16x8;
typedef __attribute__((ext_vector_type(4))) float f32x4;
typedef __attribute__((ext_vector_type(2))) float f32x2;

#define NN 50000
#define EE 1600000
#define ETOT (EE + NN)
#define NBUCK 782            // ceil(NN/64)
#define ACHUNK 8192
#define NSC ((ETOT + ACHUNK - 1) / ACHUNK)   // scatter blocks = 202
#define CAP 2432             // per-bucket capacity (mean 2112, +7 sigma)
#define NSLOT 64
#define SLOTW 260
#define GEMM_BLOCKS ((NN + 127) / 128)       // 391

__device__ __forceinline__ u16 f2bf(float f) {
  uint u = __builtin_bit_cast(uint, f);
  uint r = u + 0x7fffu + ((u >> 16) & 1u);
  return (u16)(r >> 16);
}
__device__ __forceinline__ u8 f2fp8(float f) {
  int t = __builtin_amdgcn_cvt_pk_fp8_f32(f, f, 0, false);
  return (u8)(t & 0xff);
}
__device__ __forceinline__ float wred_sum(float v) {
#pragma unroll
  for (int off = 32; off > 0; off >>= 1) v += __shfl_xor(v, off);
  return v;
}
__device__ __forceinline__ uint wred_sum_u(uint v) {
#pragma unroll
  for (int off = 32; off > 0; off >>= 1) v += __shfl_xor(v, off);
  return v;
}

// ---------------- zero: bnxt + pool slots ----------------
__global__ void zero_ws(uint* __restrict__ bnxt, float* __restrict__ slots) {
  int t = threadIdx.x;
  for (int i = t; i < NBUCK; i += 1024) bnxt[i] = 0u;
  for (int i = t; i < NSLOT * SLOTW; i += 1024) slots[i] = 0.f;
}

// ---------------- fused: bucket scatter (blocks < NSC) + W transpose (rest) ----------------
__global__ __launch_bounds__(256) void scat_wt(const int* __restrict__ esrc,
                                               const int* __restrict__ edst,
                                               uint* __restrict__ bnxt,
                                               uint* __restrict__ tmp,
                                               const float* __restrict__ W0,
                                               const float* __restrict__ W1,
                                               u16* __restrict__ Wt0,
                                               u16* __restrict__ Wt1) {
  __shared__ uint lh[NBUCK];
  if (blockIdx.x < NSC) {
    int base = blockIdx.x * ACHUNK;
    int nE = ETOT - base; if (nE > ACHUNK) nE = ACHUNK;
    for (int i = threadIdx.x; i < NBUCK; i += 256) lh[i] = 0;
    __syncthreads();
    for (int k = threadIdx.x; k < nE; k += 256) {
      int e = base + k;
      int d = (e < EE) ? edst[e] : (e - EE);
      atomicAdd(&lh[d >> 6], 1u);
    }
    __syncthreads();
    for (int i = threadIdx.x; i < NBUCK; i += 256) {
      uint c = lh[i];
      lh[i] = c ? atomicAdd(&bnxt[i], c) : 0u;
    }
    __syncthreads();
    for (int k = threadIdx.x; k < nE; k += 256) {
      int e = base + k;
      int s, d;
      if (e < EE) { s = esrc[e]; d = edst[e]; } else { s = e - EE; d = s; }
      uint pos = atomicAdd(&lh[d >> 6], 1u);
      tmp[(size_t)(d >> 6) * CAP + pos] = ((uint)(d & 63) << 16) | (uint)s;
    }
  } else {
    int i = (blockIdx.x - NSC) * 256 + threadIdx.x;
    if (i < 768 * 256) {
      int k = i >> 8, n = i & 255;
      Wt0[n * 768 + k] = f2bf(W0[i]);
    } else if (i < 768 * 256 + 256 * 256) {
      int j = i - 768 * 256;
      int k = j >> 8, n = j & 255;
      Wt1[n * 256 + k] = f2bf(W1[j]);
    }
  }
}

// ---------------- GEMM body (shared-arena based) ----------------
template <bool ABF16>
__device__ __forceinline__ void gemm_body(char* smem, int bx, const void* __restrict__ Avoid,
                                          const u16* __restrict__ Bt, u8* __restrict__ C8,
                                          const float* __restrict__ a_src,
                                          const float* __restrict__ a_dst,
                                          float* __restrict__ as_, float* __restrict__ ad_,
                                          int M, int K) {
  u16* As = (u16*)smem;                      // 16384 B
  u16* Bs = (u16*)(smem + 16384);            // 32768 B
  float* asL = (float*)(smem + 49152);       // 2048 B
  float* adL = (float*)(smem + 51200);       // 2048 B
  const int m0 = bx * 128;
  const int tid = threadIdx.x;
  const int lane = tid & 63;
  const int wv = tid >> 6;
  const int wm = wv >> 2, wn = wv & 3;

  f32x4 acc[4][4] = {};

  const int sr = tid >> 2;
  const int skc = (tid & 3) * 16;
  const int br = tid >> 1;
  const int bk = (tid & 1) * 32;

  for (int k0 = 0; k0 < K; k0 += 64) {
    {
      int grow = m0 + sr;
      if constexpr (!ABF16) {
        const float* A = (const float*)Avoid;
        float4 f[4];
        if (grow < M) {
          const float4* src = reinterpret_cast<const float4*>(A + (size_t)grow * K + k0 + skc);
#pragma unroll
          for (int i = 0; i < 4; ++i) f[i] = src[i];
        } else {
#pragma unroll
          for (int i = 0; i < 4; ++i) f[i] = make_float4(0.f, 0.f, 0.f, 0.f);
        }
#pragma unroll
        for (int i = 0; i < 2; ++i) {
          u16x8 v;
          v[0] = f2bf(f[2 * i].x); v[1] = f2bf(f[2 * i].y);
          v[2] = f2bf(f[2 * i].z); v[3] = f2bf(f[2 * i].w);
          v[4] = f2bf(f[2 * i + 1].x); v[5] = f2bf(f[2 * i + 1].y);
          v[6] = f2bf(f[2 * i + 1].z); v[7] = f2bf(f[2 * i + 1].w);
          int k = skc + i * 8;
          int idx = (sr << 6) + (k ^ ((sr & 7) << 3));
          *reinterpret_cast<u16x8*>(&As[idx]) = v;
        }
      } else {
        const u16* A = (const u16*)Avoid;
        u16x8 v[2];
        if (grow < M) {
          const u16x8* src = reinterpret_cast<const u16x8*>(A + (size_t)grow * K + k0 + skc);
          v[0] = src[0]; v[1] = src[1];
        } else {
          v[0] = (u16x8)0; v[1] = (u16x8)0;
        }
#pragma unroll
        for (int i = 0; i < 2; ++i) {
          int k = skc + i * 8;
          int idx = (sr << 6) + (k ^ ((sr & 7) << 3));
          *reinterpret_cast<u16x8*>(&As[idx]) = v[i];
        }
      }
    }
    {
      const u16x8* src = reinterpret_cast<const u16x8*>(Bt + (size_t)br * K + k0 + bk);
#pragma unroll
      for (int i = 0; i < 4; ++i) {
        u16x8 v = src[i];
        int k = bk + i * 8;
        int idx = (br << 6) + (k ^ ((br & 7) << 3));
        *reinterpret_cast<u16x8*>(&Bs[idx]) = v;
      }
    }
    __syncthreads();
#pragma unroll
    for (int kk = 0; kk < 2; ++kk) {
      short8 af[4], bfr[4];
      const int kb = kk * 32 + (lane >> 4) * 8;
#pragma unroll
      for (int m = 0; m < 4; ++m) {
        int r = wm * 64 + m * 16 + (lane & 15);
        int idx = (r << 6) + (kb ^ ((r & 7) << 3));
        af[m] = *reinterpret_cast<const short8*>(&As[idx]);
      }
#pragma unroll
      for (int n = 0; n < 4; ++n) {
        int c = wn * 64 + n * 16 + (lane & 15);
        int idx = (c << 6) + (kb ^ ((c & 7) << 3));
        bfr[n] = *reinterpret_cast<const short8*>(&Bs[idx]);
      }
#pragma unroll
      for (int m = 0; m < 4; ++m)
#pragma unroll
        for (int n = 0; n < 4; ++n)
          acc[m][n] = __builtin_amdgcn_mfma_f32_16x16x32_bf16(af[m], bfr[n], acc[m][n], 0, 0, 0);
    }
    __syncthreads();
  }

  const int g = lane >> 4;
  const int cl = lane & 15;
  float asv[4], adv[4];
#pragma unroll
  for (int n = 0; n < 4; ++n) {
    int c = wn * 64 + n * 16 + cl;
    asv[n] = a_src[c];
    adv[n] = a_dst[c];
  }
#pragma unroll
  for (int m = 0; m < 4; ++m) {
#pragma unroll
    for (int reg = 0; reg < 4; ++reg) {
      int rl = wm * 64 + m * 16 + g * 4 + reg;
      int row = m0 + rl;
      float ps = 0.f, pd = 0.f;
      if (row < M) {
#pragma unroll
        for (int n = 0; n < 4; ++n) {
          float v = acc[m][n][reg];
          C8[(size_t)row * 256 + wn * 64 + n * 16 + cl] = f2fp8(v);
          ps = fmaf(v, asv[n], ps);
          pd = fmaf(v, adv[n], pd);
        }
      }
#pragma unroll
      for (int off = 1; off < 16; off <<= 1) {
        ps += __shfl_xor(ps, off);
        pd += __shfl_xor(pd, off);
      }
      if (cl == 0) {
        asL[wn * 128 + rl] = ps;
        adL[wn * 128 + rl] = pd;
      }
    }
  }
  __syncthreads();
  if (tid < 128) {
    int row = m0 + tid;
    if (row < M) {
      as_[row] = asL[tid] + asL[128 + tid] + asL[256 + tid] + asL[384 + tid];
      ad_[row] = adL[tid] + adL[128 + tid] + adL[256 + tid] + adL[384 + tid];
    }
  }
}

// ---------------- bucket sort body (inline prefix scan; shared-arena based) ----------------
__device__ __forceinline__ void sort_body(char* smem, int b, const uint* __restrict__ tmp,
                                          const uint* __restrict__ bnxt,
                                          uint* __restrict__ row_ptr, u16* __restrict__ csr) {
  uint* lh = (uint*)smem;                    // 64 u32
  uint* red = (uint*)(smem + 256);           // 8 u32
  uint* buf = (uint*)(smem + 512);           // CAP u32
  int tid = threadIdx.x;
  int lane = tid & 63, wv = tid >> 6;

  // inline exclusive prefix: s0 = sum bnxt[0..b)
  uint part = 0;
  for (int i = tid; i < b; i += 512) part += bnxt[i];
  part = wred_sum_u(part);
  if (lane == 0) red[wv] = part;
  int cnt = (int)bnxt[b];
  if (tid < 64) lh[tid] = 0;
  __syncthreads();
  uint s0 = red[0] + red[1] + red[2] + red[3] + red[4] + red[5] + red[6] + red[7];

  for (int i = tid; i < cnt; i += 512) {
    uint v = tmp[(size_t)b * CAP + i];
    buf[i] = v;
    atomicAdd(&lh[v >> 16], 1u);
  }
  __syncthreads();
  if (tid < 64) {
    uint v = lh[tid];
    uint x = v;
#pragma unroll
    for (int off = 1; off < 64; off <<= 1) {
      uint t = __shfl_up(x, off);
      if (tid >= off) x += t;
    }
    uint pos = s0 + x - v;
    int d = b * 64 + tid;
    if (d < NN) row_ptr[d] = pos;
    lh[tid] = pos;
    if (b == NBUCK - 1 && tid == 0) row_ptr[NN] = s0 + (uint)cnt;
  }
  __syncthreads();
  for (int i = tid; i < cnt; i += 512) {
    uint v = buf[i];
    uint pos = atomicAdd(&lh[v >> 16], 1u);
    csr[pos] = (u16)(v & 0xFFFFu);
  }
}

// ---------------- fused: bucket_sort (blocks < nsort) + GEMM (rest) ----------------
template <bool ABF16>
__global__ __launch_bounds__(512) void gemm_sort(const void* __restrict__ Avoid,
                                                 const u16* __restrict__ Bt,
                                                 u8* __restrict__ C8,
                                                 const float* __restrict__ a_src,
                                                 const float* __restrict__ a_dst,
                                                 float* __restrict__ as_,
                                                 float* __restrict__ ad_,
                                                 int M, int K, int nsort,
                                                 const uint* __restrict__ tmp,
                                                 const uint* __restrict__ bnxt,
                                                 uint* __restrict__ row_ptr,
                                                 u16* __restrict__ csr) {
  __shared__ __align__(16) char smem[53248];
  if ((int)blockIdx.x < nsort) {
    sort_body(smem, blockIdx.x, tmp, bnxt, row_ptr, csr);
  } else {
    gemm_body<ABF16>(smem, blockIdx.x - nsort, Avoid, Bt, C8, a_src, a_dst, as_, ad_, M, K);
  }
}

// decode 16 fp8 from uint4 and fma into acc[16] with weight wg
#define FMA16(v, wg)                                                                   \
  do {                                                                                 \
    f32x2 p_;                                                                          \
    p_ = __builtin_amdgcn_cvt_pk_f32_fp8((v).x, false);                                \
    acc[0] = fmaf((wg), p_.x, acc[0]); acc[1] = fmaf((wg), p_.y, acc[1]);              \
    p_ = __builtin_amdgcn_cvt_pk_f32_fp8((v).x, true);                                 \
    acc[2] = fmaf((wg), p_.x, acc[2]); acc[3] = fmaf((wg), p_.y, acc[3]);              \
    p_ = __builtin_amdgcn_cvt_pk_f32_fp8((v).y, false);                                \
    acc[4] = fmaf((wg), p_.x, acc[4]); acc[5] = fmaf((wg), p_.y, acc[5]);              \
    p_ = __builtin_amdgcn_cvt_pk_f32_fp8((v).y, true);                                 \
    acc[6] = fmaf((wg), p_.x, acc[6]); acc[7] = fmaf((wg), p_.y, acc[7]);              \
    p_ = __builtin_amdgcn_cvt_pk_f32_fp8((v).z, false);                                \
    acc[8] = fmaf((wg), p_.x, acc[8]); acc[9] = fmaf((wg), p_.y, acc[9]);              \
    p_ = __builtin_amdgcn_cvt_pk_f32_fp8((v).z, true);                                 \
    acc[10] = fmaf((wg), p_.x, acc[10]); acc[11] = fmaf((wg), p_.y, acc[11]);          \
    p_ = __builtin_amdgcn_cvt_pk_f32_fp8((v).w, false);                                \
    acc[12] = fmaf((wg), p_.x, acc[12]); acc[13] = fmaf((wg), p_.y, acc[13]);          \
    p_ = __builtin_amdgcn_cvt_pk_f32_fp8((v).w, true);                                 \
    acc[14] = fmaf((wg), p_.x, acc[14]); acc[15] = fmaf((wg), p_.y, acc[15]);          \
  } while (0)

// ---------------- GAT aggregation (fp8 gather, 4 loads in flight); POOL fuses pooling ----------------
template <bool POOL>
__global__ __launch_bounds__(256) void agg_kernel(const uint4* __restrict__ h16,
                                                  const float* __restrict__ as_,
                                                  const float* __restrict__ ad_,
                                                  const uint* __restrict__ row_ptr,
                                                  const u16* __restrict__ csr_src,
                                                  const float* __restrict__ bias,
                                                  u16* __restrict__ out,
                                                  const float* __restrict__ gate_w,
                                                  float* __restrict__ slots, int n) {
  __shared__ float tr[4][4][16][17];
  __shared__ float lp[257];
  int wv = threadIdx.x >> 6;
  int wid = blockIdx.x * 4 + wv;
  int lane = threadIdx.x & 63;
  int g = lane >> 4, li = lane & 15;
  if (POOL) {
    for (int i = threadIdx.x; i < 257; i += 256) lp[i] = 0.f;
    __syncthreads();
  }
  if (wid < n) {
    uint start = row_ptr[wid], end = row_ptr[wid + 1];
    float adi = ad_[wid];
    float acc[16];
#pragma unroll
    for (int c = 0; c < 16; ++c) acc[c] = 0.f;
    float denom = 0.f;
    for (uint base = start; base < end; base += 64) {
      int cnt = (int)(end - base);
      if (cnt > 64) cnt = 64;
      float w = 0.f;
      int s = 0;
      if (lane < cnt) {
        s = (int)csr_src[base + lane];
        float e = as_[s] + adi;
        e = e > 0.f ? e : 0.2f * e;
        w = __expf(e);
      }
      denom += w;
      int j = 0;
      for (; j + 16 <= cnt; j += 16) {
        int s0 = __shfl(s, j + g);
        int s1 = __shfl(s, j + 4 + g);
        int s2 = __shfl(s, j + 8 + g);
        int s3 = __shfl(s, j + 12 + g);
        float w0 = __shfl(w, j + g);
        float w1 = __shfl(w, j + 4 + g);
        float w2 = __shfl(w, j + 8 + g);
        float w3 = __shfl(w, j + 12 + g);
        uint4 v0 = h16[(size_t)s0 * 16 + li];
        uint4 v1 = h16[(size_t)s1 * 16 + li];
        uint4 v2 = h16[(size_t)s2 * 16 + li];
        uint4 v3 = h16[(size_t)s3 * 16 + li];
        FMA16(v0, w0);
        FMA16(v1, w1);
        FMA16(v2, w2);
        FMA16(v3, w3);
      }
      for (; j < cnt; j += 4) {
        int jg = j + g;
        int sg = __shfl(s, jg & 63);
        float wg = __shfl(w, jg & 63);
        if (jg >= cnt) wg = 0.f;
        uint4 v = h16[(size_t)sg * 16 + li];
        FMA16(v, wg);
      }
    }
    denom = wred_sum(denom);
#pragma unroll
    for (int c4 = 0; c4 < 4; ++c4)
      *reinterpret_cast<float4*>(&tr[wv][g][li][c4 * 4]) =
          make_float4(acc[c4 * 4], acc[c4 * 4 + 1], acc[c4 * 4 + 2], acc[c4 * 4 + 3]);
    asm volatile("s_waitcnt lgkmcnt(0)" ::: "memory");
    __builtin_amdgcn_sched_barrier(0);
    float ax = 0.f, ay = 0.f, az = 0.f, aw = 0.f;
#pragma unroll
    for (int gg = 0; gg < 4; ++gg) {
      const float* r = &tr[wv][gg][lane >> 2][4 * (lane & 3)];
      ax += r[0]; ay += r[1]; az += r[2]; aw += r[3];
    }
    float inv = 1.f / (denom + 1e-16f);
    float4 b = reinterpret_cast<const float4*>(bias)[lane];
    float ox = fmaxf(fmaf(ax, inv, b.x), 0.f);
    float oy = fmaxf(fmaf(ay, inv, b.y), 0.f);
    float oz = fmaxf(fmaf(az, inv, b.z), 0.f);
    float ow = fmaxf(fmaf(aw, inv, b.w), 0.f);
    if (!POOL) {
      ushort4 o;
      o.x = f2bf(ox); o.y = f2bf(oy); o.z = f2bf(oz); o.w = f2bf(ow);
      reinterpret_cast<ushort4*>(out)[(size_t)wid * 64 + lane] = o;
    } else {
      float4 gv = reinterpret_cast<const float4*>(gate_w)[lane];
      float pg = wred_sum(ox * gv.x + oy * gv.y + oz * gv.z + ow * gv.w);
      float we = __expf(pg);
      int c0 = lane * 4;
      atomicAdd(&lp[c0 + 0], we * ox);
      atomicAdd(&lp[c0 + 1], we * oy);
      atomicAdd(&lp[c0 + 2], we * oz);
      atomicAdd(&lp[c0 + 3], we * ow);
      if (lane == 0) atomicAdd(&lp[256], we);
    }
  }
  if (POOL) {
    __syncthreads();
    int slot = blockIdx.x & (NSLOT - 1);
    for (int i = threadIdx.x; i < 257; i += 256) {
      float v = lp[i];
      if (v != 0.f) atomicAdd(&slots[slot * SLOTW + i], v);
    }
  }
}

// ---------------- final: reduce slots, normalize ----------------
__global__ void pool3_kernel(const float* __restrict__ slots, float* __restrict__ out) {
  __shared__ float dsh;
  int tid = threadIdx.x;
  float acc = 0.f;
  for (int s = 0; s < NSLOT; ++s) acc += slots[s * SLOTW + tid];
  if (tid == 0) {
    float d = 0.f;
    for (int s = 0; s < NSLOT; ++s) d += slots[s * SLOTW + 256];
    dsh = d;
  }
  __syncthreads();
  out[tid] = acc / dsh;
}

// ---------------- launch ----------------
extern "C" void kernel_launch(void* const* d_in, const int* in_sizes, int n_in,
                              void* d_out, int out_size, void* d_ws, size_t ws_size,
                              hipStream_t stream) {
  const float* x = (const float*)d_in[0];
  const int* edge = (const int*)d_in[1];
  const float* W0 = (const float*)d_in[2];
  const float* a_src0 = (const float*)d_in[3];
  const float* a_dst0 = (const float*)d_in[4];
  const float* b0 = (const float*)d_in[5];
  const float* W1 = (const float*)d_in[6];
  const float* a_src1 = (const float*)d_in[7];
  const float* a_dst1 = (const float*)d_in[8];
  const float* b1 = (const float*)d_in[9];
  const float* gate_w = (const float*)d_in[10];
  float* out = (float*)d_out;

  char* p = (char*)d_ws;
  size_t off = 0;
  auto take = [&](size_t bytes) -> char* {
    char* r = p + off;
    off = (off + bytes + 255) & ~(size_t)255;
    return r;
  };
  u8* hA = (u8*)take((size_t)NN * 256);          // fp8 h (GEMM out, gather operand)
  u16* hB = (u16*)take((size_t)NN * 256 * 2);    // bf16 agg0 out (gemm1 input)
  u16* Wt0 = (u16*)take((size_t)256 * 768 * 2);
  u16* Wt1 = (u16*)take((size_t)256 * 256 * 2);
  float* as0 = (float*)take((size_t)NN * 4);
  float* ad0 = (float*)take((size_t)NN * 4);
  float* as1 = (float*)take((size_t)NN * 4);
  float* ad1 = (float*)take((size_t)NN * 4);
  float* slots = (float*)take((size_t)NSLOT * SLOTW * 4);
  uint* bnxt = (uint*)take((size_t)NBUCK * 4);
  uint* row_ptr = (uint*)take((size_t)(NN + 1) * 4);
  uint* tmp = (uint*)take((size_t)NBUCK * CAP * 4);
  u16* csr = (u16*)take((size_t)ETOT * 2);

  const int* edge_src = edge;
  const int* edge_dst = edge + EE;

  zero_ws<<<1, 1024, 0, stream>>>(bnxt, slots);
  scat_wt<<<NSC + 1024, 256, 0, stream>>>(edge_src, edge_dst, bnxt, tmp, W0, W1, Wt0, Wt1);

  // layer 0 GEMM fused with bucket_sort (independent work, hidden under GEMM)
  gemm_sort<false><<<NBUCK + GEMM_BLOCKS, 512, 0, stream>>>(
      x, Wt0, hA, a_src0, a_dst0, as0, ad0, NN, 768, NBUCK, tmp, bnxt, row_ptr, csr);
  agg_kernel<false><<<12500, 256, 0, stream>>>((const uint4*)hA, as0, ad0, row_ptr, csr, b0, hB,
                                               gate_w, slots, NN);
  gemm_sort<true><<<GEMM_BLOCKS, 512, 0, stream>>>(
      hB, Wt1, hA, a_src1, a_dst1, as1, ad1, NN, 256, 0, tmp, bnxt, row_ptr, csr);
  agg_kernel<true><<<12500, 256, 0, stream>>>((const uint4*)hA, as1, ad1, row_ptr, csr, b1, nullptr,
                                              gate_w, slots, NN);

  pool3_kernel<<<1, 256, 0, stream>>>(slots, out);
}